// Round 1
// baseline (6822.565 us; speedup 1.0000x reference)
//
#include <hip/hip_runtime.h>
#include <stdint.h>

#define TT 400
#define BB 256
#define II 256
#define HH 512
#define NG 2048  // 4*H

typedef __attribute__((ext_vector_type(8))) short short8;
typedef __attribute__((ext_vector_type(4))) float f32x4;
typedef unsigned int u32;
typedef unsigned short u16;

static __device__ __forceinline__ u16 f2bf(float f){
  u32 u = __float_as_uint(f);
  u += 0x7fffu + ((u >> 16) & 1u);   // RNE
  return (u16)(u >> 16);
}
static __device__ __forceinline__ float bf2f(u16 b){ return __uint_as_float(((u32)b) << 16); }

#define GLOAD16(gsrc, ldst) \
  __builtin_amdgcn_global_load_lds((const __attribute__((address_space(1))) void*)(gsrc), \
                                   (__attribute__((address_space(3))) void*)(ldst), 16, 0, 0)

// ---------------------------------------------------------------------------
// Transpose x[B][I][T] fp32 -> xT2[t][b][2i]=hi,[2i+1]=lo (bf16 interleaved).
// Tile 16(i) x 16(t) per block, 1 elem/thread. Reads 64B-coalesced along t.
__global__ __launch_bounds__(256) void k_prep_x(const float* __restrict__ x,
                                                u16* __restrict__ xT2){
  __shared__ float tile[16][17];
  const int bid = blockIdx.x;
  const int tb = bid % 25, ib = (bid / 25) & 15, b = bid / 400;
  const int t0 = tb * 16, i0 = ib * 16;
  const int tl = threadIdx.x & 15, il = threadIdx.x >> 4;
  tile[il][tl] = x[(size_t)(b * II + i0 + il) * TT + t0 + tl];
  __syncthreads();
  const int trow = il, i = tl;
  const float w = tile[i][trow];
  const u16 hi = f2bf(w);
  const u16 lo = f2bf(w - bf2f(hi));
  const u32 pack = (u32)hi | ((u32)lo << 16);
  *(u32*)(xT2 + ((size_t)(t0 + trow) * BB + b) * 512 + 2 * (i0 + i)) = pack;
}

// ---------------------------------------------------------------------------
// w_ih[4H][I] fp32 -> Wp[n][2k]=Wp[n][2k+1]=bf16(w) (duplicated to match the
// interleaved hi/lo A operand).
__global__ __launch_bounds__(256) void k_prep_w(const float* __restrict__ w_ih,
                                                u16* __restrict__ Wp){
  const int idx = blockIdx.x * 256 + threadIdx.x;  // 0..131071
  const int n = idx >> 6, c = idx & 63;
  const float4 v = *(const float4*)(w_ih + (size_t)n * II + c * 4);
  uint4 o;
  o.x = (u32)f2bf(v.x) * 0x10001u;
  o.y = (u32)f2bf(v.y) * 0x10001u;
  o.z = (u32)f2bf(v.z) * 0x10001u;
  o.w = (u32)f2bf(v.w) * 0x10001u;
  *(uint4*)(Wp + (size_t)n * 512 + c * 8) = o;
}

// ---------------------------------------------------------------------------
// xg[M=102400][2048] (fp16) = A[M][512] @ Wp[2048][512]^T, bf16 MFMA.
// m97-style: 128x128 tile, BK=64, double-buffered LDS via global_load_lds(16B),
// XOR-swizzled (s ^= row&7 on 16B units) staging + reads.
__global__ __launch_bounds__(256) void k_gemm_xg(const u16* __restrict__ A,
                                                 const u16* __restrict__ B,
                                                 _Float16* __restrict__ xg){
  __shared__ char lds[65536];  // A: buf*16384 ; B: 32768 + buf*16384
  const int tid = threadIdx.x, w = tid >> 6, lane = tid & 63;
  const int nb = blockIdx.x & 15, mb = blockIdx.x >> 4;
  const size_t m0 = (size_t)mb * 128;
  const int n0 = nb * 128;
  const int lr = lane & 15, lh = lane >> 4;

  auto stage = [&](int it, int buf){
    const size_t kb = (size_t)it * 128;
    #pragma unroll
    for (int i2 = 0; i2 < 4; ++i2){
      const int u = w * 256 + i2 * 64 + lane;
      const int r = u >> 3, s = u & 7;
      const char* g = (const char*)A + (m0 + r) * 1024 + kb + ((s ^ (r & 7)) << 4);
      char* l = lds + buf * 16384 + ((w * 256 + i2 * 64) << 4);
      GLOAD16(g, l);
    }
    #pragma unroll
    for (int i2 = 0; i2 < 4; ++i2){
      const int u = w * 256 + i2 * 64 + lane;
      const int r = u >> 3, s = u & 7;
      const char* g = (const char*)B + (size_t)(n0 + r) * 1024 + kb + ((s ^ (r & 7)) << 4);
      char* l = lds + 32768 + buf * 16384 + ((w * 256 + i2 * 64) << 4);
      GLOAD16(g, l);
    }
  };

  f32x4 acc[4][4];
  #pragma unroll
  for (int i = 0; i < 4; ++i)
    #pragma unroll
    for (int j = 0; j < 4; ++j){ f32x4 z = {0.f,0.f,0.f,0.f}; acc[i][j] = z; }

  const int wm = (w & 1) * 64, wn = (w >> 1) * 64;
  stage(0, 0);
  for (int it = 0; it < 8; ++it){
    const int buf = it & 1;
    if (it < 7) stage(it + 1, buf ^ 1);
    __syncthreads();               // compiler drains vmcnt(0) -> current tiles ready
    const char* lA = lds + buf * 16384;
    const char* lB = lds + 32768 + buf * 16384;
    #pragma unroll
    for (int ks = 0; ks < 2; ++ks){
      short8 a[4], b[4];
      const int s = ks * 4 + lh;
      #pragma unroll
      for (int mt = 0; mt < 4; ++mt){
        const int r = wm + mt * 16 + lr;
        a[mt] = *(const short8*)(lA + r * 128 + ((s ^ (r & 7)) << 4));
      }
      #pragma unroll
      for (int nt = 0; nt < 4; ++nt){
        const int r = wn + nt * 16 + lr;
        b[nt] = *(const short8*)(lB + r * 128 + ((s ^ (r & 7)) << 4));
      }
      #pragma unroll
      for (int mt = 0; mt < 4; ++mt)
        #pragma unroll
        for (int nt = 0; nt < 4; ++nt)
          acc[mt][nt] = __builtin_amdgcn_mfma_f32_16x16x32_bf16(a[mt], b[nt], acc[mt][nt], 0, 0, 0);
    }
    __syncthreads();               // reads done before next stage overwrites
  }
  // epilogue: C/D layout col=lane&15, row=(lane>>4)*4+reg
  #pragma unroll
  for (int mt = 0; mt < 4; ++mt)
    #pragma unroll
    for (int nt = 0; nt < 4; ++nt)
      #pragma unroll
      for (int r = 0; r < 4; ++r){
        const size_t row = m0 + wm + mt * 16 + lh * 4 + r;
        const int col = n0 + wn + nt * 16 + lr;
        xg[row * NG + col] = (_Float16)acc[mt][nt][r];
      }
}

// ---------------------------------------------------------------------------
// Persistent recurrent kernel. 256 WGs x 512 thr (8 waves), 160KB LDS each ->
// 1 WG/CU (co-resident). WG (gb,gn): batch rows [gb*16,+16), h-cols [gn*32,+32)
// i.e. gate rows {q*512+j0..+32}. w_hh slice lives in LDS for all 400 steps.
// Intra-batch-group sync: one counter per group, release/acquire AGENT scope.
__global__ __launch_bounds__(512) void k_lstm(const _Float16* __restrict__ xg,
    const float* __restrict__ w_hh, const float* __restrict__ b_ih,
    const float* __restrict__ b_hh, u16* __restrict__ h_hi, u16* __restrict__ h_lo,
    u32* __restrict__ cnt, float* __restrict__ out){
  extern __shared__ char lds[];
  char* Wl  = lds;                         // 131072 B: [128 rows][512 bf16] swizzled
  char* hb  = lds + 131072;                // 16384 B: h_hi stage [16][512] swizzled
  char* hb2 = lds + 147456;                // 16384 B: h_lo stage
  float* gbuf = (float*)(lds + 131072);    // 8192 B, aliases hb (barrier-separated)

  const int tid = threadIdx.x, w = tid >> 6, lane = tid & 63;
  const int lr = lane & 15, lh = lane >> 4;
  const int gb = blockIdx.x >> 4, gn = blockIdx.x & 15;
  const int b0 = gb * 16, j0 = gn * 32;
  u32* mycnt = cnt + gb * 64;

  // ---- load + convert + swizzle the w_hh slice into LDS (once)
  for (int rep = 0; rep < 32; ++rep){
    const int idx = rep * 512 + tid;       // 0..16383 float4s
    const int row = idx >> 7, c4 = idx & 127;
    const int grow = ((row >> 5) << 9) + j0 + (row & 31);
    const float4 v = *(const float4*)(w_hh + (size_t)grow * HH + c4 * 4);
    uint2 p;
    p.x = (u32)f2bf(v.x) | ((u32)f2bf(v.y) << 16);
    p.y = (u32)f2bf(v.z) | ((u32)f2bf(v.w) << 16);
    const int off = row * 1024 + ((((c4 >> 1) ^ (row & 7)) << 4) | ((c4 & 1) << 3));
    *(uint2*)(Wl + off) = p;
  }
  const int jj = tid & 31, brow = tid >> 5;       // this thread's (b-row, h-col)
  float bias_[4];
  #pragma unroll
  for (int q = 0; q < 4; ++q) bias_[q] = b_ih[q * HH + j0 + jj] + b_hh[q * HH + j0 + jj];
  float c = 0.f;
  const int q = w >> 1, jb = w & 1;
  __syncthreads();

  for (int t = 0; t < TT; ++t){
    const bool has_h = (t > 0);
    if (has_h){
      if (tid == 0){
        const u32 target = (u32)(16 * t);
        while (__hip_atomic_load(mycnt, __ATOMIC_ACQUIRE, __HIP_MEMORY_SCOPE_AGENT) < target)
          __builtin_amdgcn_s_sleep(1);
      }
      __syncthreads();
      // stage h[t-1] (hi/lo) into LDS, XOR-swizzled
      const size_t par = (size_t)((t - 1) & 1) * (BB * HH);
      const char* ghi = (const char*)(h_hi + par);
      const char* glo = (const char*)(h_lo + par);
      #pragma unroll
      for (int rep = 0; rep < 2; ++rep){
        const int u = rep * 512 + tid;     // 0..1023 16B units
        const int r = u >> 6, s = u & 63;
        const int gby = (b0 + r) * 1024 + s * 16;
        const int lby = r * 1024 + ((s ^ (r & 7)) << 4);
        *(uint4*)(hb + lby)  = *(const uint4*)(ghi + gby);
        *(uint4*)(hb2 + lby) = *(const uint4*)(glo + gby);
      }
      __syncthreads();
      // gates(q, jb-half) = (h_hi + h_lo) @ W^T ; wave owns one 16x16 tile
      f32x4 acc = {0.f, 0.f, 0.f, 0.f};
      const int nrow = q * 32 + jb * 16 + lr;
      const int nbase = nrow * 1024, nx = nrow & 7;
      #pragma unroll
      for (int ks = 0; ks < 16; ++ks){
        const int s = ks * 4 + lh;
        const int aoff = lr * 1024 + ((s ^ (lr & 7)) << 4);
        const short8 ahi = *(const short8*)(hb + aoff);
        const short8 alo = *(const short8*)(hb2 + aoff);
        const short8 bv  = *(const short8*)(Wl + nbase + ((s ^ nx) << 4));
        acc = __builtin_amdgcn_mfma_f32_16x16x32_bf16(ahi, bv, acc, 0, 0, 0);
        acc = __builtin_amdgcn_mfma_f32_16x16x32_bf16(alo, bv, acc, 0, 0, 0);
      }
      __syncthreads();   // all waves done reading hb/hb2 (gbuf aliases them)
      {
        const int mrow = lh * 4;
        #pragma unroll
        for (int r = 0; r < 4; ++r)
          gbuf[(q * 16 + mrow + r) * 32 + jb * 16 + lr] = acc[r];
      }
      __syncthreads();
    }
    // ---- pointwise LSTM cell (one (b,j) per thread, c held in register)
    const _Float16* xt = xg + (size_t)t * (BB * NG) + (size_t)(b0 + brow) * NG + j0 + jj;
    float g4[4];
    #pragma unroll
    for (int qq = 0; qq < 4; ++qq){
      float gg = (float)xt[qq * HH] + bias_[qq];
      if (has_h) gg += gbuf[(qq * 16 + brow) * 32 + jj];
      g4[qq] = gg;
    }
    const float i_ = 1.f / (1.f + __expf(-g4[0]));
    const float f_ = 1.f / (1.f + __expf(-g4[1]));
    const float ea = __expf(-2.f * fabsf(g4[2]));
    const float g_ = __builtin_copysignf((1.f - ea) / (1.f + ea), g4[2]);
    const float o_ = 1.f / (1.f + __expf(-g4[3]));
    c = f_ * c + i_ * g_;
    out[(size_t)t * (BB * HH) + (size_t)(b0 + brow) * HH + j0 + jj] = c;
    const float eb = __expf(-2.f * fabsf(c));
    const float th = __builtin_copysignf((1.f - eb) / (1.f + eb), c);
    const float hn = o_ * th;
    {
      const size_t par = (size_t)(t & 1) * (BB * HH);
      const u16 hv = f2bf(hn);
      const float lo = hn - bf2f(hv);
      const size_t hoff = par + (size_t)(b0 + brow) * HH + j0 + jj;
      h_hi[hoff] = hv;
      h_lo[hoff] = f2bf(lo);
    }
    if (t < TT - 1){
      __syncthreads();   // drains all waves' h stores (vmcnt 0) before publish
      if (tid == 0) __hip_atomic_fetch_add(mycnt, 1u, __ATOMIC_RELEASE, __HIP_MEMORY_SCOPE_AGENT);
    }
  }
}

// ---------------------------------------------------------------------------
extern "C" void kernel_launch(void* const* d_in, const int* in_sizes, int n_in,
                              void* d_out, int out_size, void* d_ws, size_t ws_size,
                              hipStream_t stream){
  const float* x    = (const float*)d_in[0];
  const float* w_ih = (const float*)d_in[1];
  const float* w_hh = (const float*)d_in[2];
  const float* b_ih = (const float*)d_in[3];
  const float* b_hh = (const float*)d_in[4];
  float* out = (float*)d_out;
  char* ws = (char*)d_ws;

  const size_t o_xg  = 0;             // fp16 [400][256][2048]   = 419,430,400 B
  const size_t o_xt2 = 419430400;     // bf16 [400][256][512]    = 104,857,600 B
  const size_t o_wp  = 524288000;     // bf16 [2048][512]        =   2,097,152 B
  const size_t o_hhi = 526385152;     // bf16 [2][256][512]      =     524,288 B
  const size_t o_hlo = 526909440;     //                         =     524,288 B
  const size_t o_cnt = 527433728;     // u32 counters, 16 x 256B =       4,096 B
  const size_t need  = 527437824;
  if (ws_size < need) return;         // insufficient scratch -> loud fail

  _Float16* xg = (_Float16*)(ws + o_xg);
  u16* xt2 = (u16*)(ws + o_xt2);
  u16* wp  = (u16*)(ws + o_wp);
  u16* hhi = (u16*)(ws + o_hhi);
  u16* hlo = (u16*)(ws + o_hlo);
  u32* cnt = (u32*)(ws + o_cnt);

  hipMemsetAsync(cnt, 0, 4096, stream);
  hipLaunchKernelGGL(k_prep_x, dim3(102400), dim3(256), 0, stream, x, xt2);
  hipLaunchKernelGGL(k_prep_w, dim3(512), dim3(256), 0, stream, w_ih, wp);
  hipLaunchKernelGGL(k_gemm_xg, dim3(12800), dim3(256), 0, stream, xt2, wp, xg);
  hipLaunchKernelGGL(k_lstm, dim3(256), dim3(512), 163840, stream,
                     xg, w_hh, b_ih, b_hh, hhi, hlo, cnt, out);
}

// Round 2
// 1945.870 us; speedup vs baseline: 3.5062x; 3.5062x over previous
//
#include <hip/hip_runtime.h>
#include <stdint.h>

#define TT 400
#define BB 256
#define II 256
#define HH 512
#define NG 2048  // 4*H

typedef __attribute__((ext_vector_type(8))) short short8;
typedef __attribute__((ext_vector_type(4))) float f32x4;
typedef __attribute__((ext_vector_type(4))) unsigned int u32x4;
typedef unsigned int u32;
typedef unsigned short u16;

static __device__ __forceinline__ u16 f2bf(float f){
  u32 u = __float_as_uint(f);
  u += 0x7fffu + ((u >> 16) & 1u);   // RNE
  return (u16)(u >> 16);
}
static __device__ __forceinline__ float bf2f(u16 b){ return __uint_as_float(((u32)b) << 16); }

#define GLOAD16(gsrc, ldst) \
  __builtin_amdgcn_global_load_lds((const __attribute__((address_space(1))) void*)(gsrc), \
                                   (__attribute__((address_space(3))) void*)(ldst), 16, 0, 0)

// ---------------------------------------------------------------------------
// Transpose x[B][I][T] fp32 -> xT2[t][b][2i]=hi,[2i+1]=lo (bf16 interleaved).
__global__ __launch_bounds__(256) void k_prep_x(const float* __restrict__ x,
                                                u16* __restrict__ xT2){
  __shared__ float tile[16][17];
  const int bid = blockIdx.x;
  const int tb = bid % 25, ib = (bid / 25) & 15, b = bid / 400;
  const int t0 = tb * 16, i0 = ib * 16;
  const int tl = threadIdx.x & 15, il = threadIdx.x >> 4;
  tile[il][tl] = x[(size_t)(b * II + i0 + il) * TT + t0 + tl];
  __syncthreads();
  const int trow = il, i = tl;
  const float w = tile[i][trow];
  const u16 hi = f2bf(w);
  const u16 lo = f2bf(w - bf2f(hi));
  const u32 pack = (u32)hi | ((u32)lo << 16);
  *(u32*)(xT2 + ((size_t)(t0 + trow) * BB + b) * 512 + 2 * (i0 + i)) = pack;
}

// ---------------------------------------------------------------------------
// w_ih[4H][I] fp32 -> Wp[n][2k]=Wp[n][2k+1]=bf16(w) (duplicated pair layout).
__global__ __launch_bounds__(256) void k_prep_w(const float* __restrict__ w_ih,
                                                u16* __restrict__ Wp){
  const int idx = blockIdx.x * 256 + threadIdx.x;  // 0..131071
  const int n = idx >> 6, c = idx & 63;
  const float4 v = *(const float4*)(w_ih + (size_t)n * II + c * 4);
  uint4 o;
  o.x = (u32)f2bf(v.x) * 0x10001u;
  o.y = (u32)f2bf(v.y) * 0x10001u;
  o.z = (u32)f2bf(v.z) * 0x10001u;
  o.w = (u32)f2bf(v.w) * 0x10001u;
  *(uint4*)(Wp + (size_t)n * 512 + c * 8) = o;
}

// ---------------------------------------------------------------------------
// xg[M=102400][2048] (fp16) = A[M][512] @ Wp[2048][512]^T, bf16 MFMA.
__global__ __launch_bounds__(256) void k_gemm_xg(const u16* __restrict__ A,
                                                 const u16* __restrict__ B,
                                                 _Float16* __restrict__ xg){
  __shared__ char lds[65536];  // A: buf*16384 ; B: 32768 + buf*16384
  const int tid = threadIdx.x, w = tid >> 6, lane = tid & 63;
  const int nb = blockIdx.x & 15, mb = blockIdx.x >> 4;
  const size_t m0 = (size_t)mb * 128;
  const int n0 = nb * 128;
  const int lr = lane & 15, lh = lane >> 4;

  auto stage = [&](int it, int buf){
    const size_t kb = (size_t)it * 128;
    #pragma unroll
    for (int i2 = 0; i2 < 4; ++i2){
      const int u = w * 256 + i2 * 64 + lane;
      const int r = u >> 3, s = u & 7;
      const char* g = (const char*)A + (m0 + r) * 1024 + kb + ((s ^ (r & 7)) << 4);
      char* l = lds + buf * 16384 + ((w * 256 + i2 * 64) << 4);
      GLOAD16(g, l);
    }
    #pragma unroll
    for (int i2 = 0; i2 < 4; ++i2){
      const int u = w * 256 + i2 * 64 + lane;
      const int r = u >> 3, s = u & 7;
      const char* g = (const char*)B + (size_t)(n0 + r) * 1024 + kb + ((s ^ (r & 7)) << 4);
      char* l = lds + 32768 + buf * 16384 + ((w * 256 + i2 * 64) << 4);
      GLOAD16(g, l);
    }
  };

  f32x4 acc[4][4];
  #pragma unroll
  for (int i = 0; i < 4; ++i)
    #pragma unroll
    for (int j = 0; j < 4; ++j){ f32x4 z = {0.f,0.f,0.f,0.f}; acc[i][j] = z; }

  const int wm = (w & 1) * 64, wn = (w >> 1) * 64;
  stage(0, 0);
  for (int it = 0; it < 8; ++it){
    const int buf = it & 1;
    if (it < 7) stage(it + 1, buf ^ 1);
    __syncthreads();
    const char* lA = lds + buf * 16384;
    const char* lB = lds + 32768 + buf * 16384;
    #pragma unroll
    for (int ks = 0; ks < 2; ++ks){
      short8 a[4], b[4];
      const int s = ks * 4 + lh;
      #pragma unroll
      for (int mt = 0; mt < 4; ++mt){
        const int r = wm + mt * 16 + lr;
        a[mt] = *(const short8*)(lA + r * 128 + ((s ^ (r & 7)) << 4));
      }
      #pragma unroll
      for (int nt = 0; nt < 4; ++nt){
        const int r = wn + nt * 16 + lr;
        b[nt] = *(const short8*)(lB + r * 128 + ((s ^ (r & 7)) << 4));
      }
      #pragma unroll
      for (int mt = 0; mt < 4; ++mt)
        #pragma unroll
        for (int nt = 0; nt < 4; ++nt)
          acc[mt][nt] = __builtin_amdgcn_mfma_f32_16x16x32_bf16(a[mt], b[nt], acc[mt][nt], 0, 0, 0);
    }
    __syncthreads();
  }
  #pragma unroll
  for (int mt = 0; mt < 4; ++mt)
    #pragma unroll
    for (int nt = 0; nt < 4; ++nt)
      #pragma unroll
      for (int r = 0; r < 4; ++r){
        const size_t row = m0 + wm + mt * 16 + lh * 4 + r;
        const int col = n0 + wn + nt * 16 + lr;
        xg[row * NG + col] = (_Float16)acc[mt][nt][r];
      }
}

// ---------------------------------------------------------------------------
// Persistent recurrent kernel, device-coherent (sc0 sc1 / MALL) h-exchange.
// No L2 writebacks/invalidates: only the h buffers + flag bypass the caches.
__global__ __launch_bounds__(512) void k_lstm(const _Float16* __restrict__ xg,
    const float* __restrict__ w_hh, const float* __restrict__ b_ih,
    const float* __restrict__ b_hh, u16* __restrict__ h_hi, u16* __restrict__ h_lo,
    u32* __restrict__ cnt, float* __restrict__ out){
  extern __shared__ char lds[];
  char* Wl  = lds;                         // 131072 B: [128 rows][512 bf16] swizzled
  char* hb  = lds + 131072;                // 16384 B: h_hi stage [16][512] swizzled
  char* hb2 = lds + 147456;                // 16384 B: h_lo stage
  float* gbuf = (float*)(lds + 131072);    // 8192 B, aliases hb (barrier-separated)

  const int tid = threadIdx.x, w = tid >> 6, lane = tid & 63;
  const int lr = lane & 15, lh = lane >> 4;
  const int gb = blockIdx.x >> 4, gn = blockIdx.x & 15;
  const int b0 = gb * 16, j0 = gn * 32;
  u32* mycnt = cnt + gb * 64;

  // ---- load + convert + swizzle the w_hh slice into LDS (once)
  for (int rep = 0; rep < 32; ++rep){
    const int idx = rep * 512 + tid;       // 0..16383 float4s
    const int row = idx >> 7, c4 = idx & 127;
    const int grow = ((row >> 5) << 9) + j0 + (row & 31);
    const float4 v = *(const float4*)(w_hh + (size_t)grow * HH + c4 * 4);
    uint2 p;
    p.x = (u32)f2bf(v.x) | ((u32)f2bf(v.y) << 16);
    p.y = (u32)f2bf(v.z) | ((u32)f2bf(v.w) << 16);
    const int off = row * 1024 + ((((c4 >> 1) ^ (row & 7)) << 4) | ((c4 & 1) << 3));
    *(uint2*)(Wl + off) = p;
  }
  const int jj = tid & 31, brow = tid >> 5;
  float bias_[4];
  #pragma unroll
  for (int q = 0; q < 4; ++q) bias_[q] = b_ih[q * HH + j0 + jj] + b_hh[q * HH + j0 + jj];
  float c = 0.f;
  const int q = w >> 1, jb = w & 1;

  // precomputed stage addressing (invariant; only parity base changes)
  const int u2i = 512 + tid;
  const int r1 = tid >> 6, s1 = tid & 63;
  const int r2 = u2i >> 6, s2 = u2i & 63;
  const size_t gof1 = (size_t)(b0 + r1) * 1024 + s1 * 16;
  const size_t gof2 = (size_t)(b0 + r2) * 1024 + s2 * 16;
  const int lof1 = r1 * 1024 + ((s1 ^ (r1 & 7)) << 4);
  const int lof2 = r2 * 1024 + ((s2 ^ (r2 & 7)) << 4);
  __syncthreads();

  for (int t = 0; t < TT; ++t){
    // ---- xg prefetch into registers (hides HBM latency under the wait)
    const _Float16* xt = xg + (size_t)t * (BB * NG) + (size_t)(b0 + brow) * NG + j0 + jj;
    u32 xv0, xv1, xv2, xv3;
    asm volatile(
      "global_load_ushort %0, %4, off\n\t"
      "global_load_ushort %1, %5, off\n\t"
      "global_load_ushort %2, %6, off\n\t"
      "global_load_ushort %3, %7, off"
      : "=&v"(xv0), "=&v"(xv1), "=&v"(xv2), "=&v"(xv3)
      : "v"(xt), "v"(xt + HH), "v"(xt + 2 * HH), "v"(xt + 3 * HH)
      : "memory");

    if (t > 0){
      if (tid == 0){
        const u32 target = (u32)(16 * t);
        u32 v; int guard = 0;
        do {
          asm volatile("s_sleep 1");
          asm volatile("global_load_dword %0, %1, off sc0 sc1\n\t"
                       "s_waitcnt vmcnt(0)"
                       : "=v"(v) : "v"(mycnt) : "memory");
        } while (v < target && ++guard < (1 << 22));
      }
      __syncthreads();
      // stage h[t-1] (hi/lo) into LDS via device-coherent loads
      const size_t par = (size_t)((t - 1) & 1) * (BB * HH);
      const char* ghi = (const char*)(h_hi + par);
      const char* glo = (const char*)(h_lo + par);
      u32x4 a1, a2, a3, a4;
      asm volatile(
        "global_load_dwordx4 %0, %4, off sc0 sc1\n\t"
        "global_load_dwordx4 %1, %5, off sc0 sc1\n\t"
        "global_load_dwordx4 %2, %6, off sc0 sc1\n\t"
        "global_load_dwordx4 %3, %7, off sc0 sc1\n\t"
        "s_waitcnt vmcnt(0)"
        : "=&v"(a1), "=&v"(a2), "=&v"(a3), "=&v"(a4)
        : "v"(ghi + gof1), "v"(ghi + gof2), "v"(glo + gof1), "v"(glo + gof2)
        : "memory");
      *(u32x4*)(hb + lof1)  = a1;
      *(u32x4*)(hb + lof2)  = a2;
      *(u32x4*)(hb2 + lof1) = a3;
      *(u32x4*)(hb2 + lof2) = a4;
      __syncthreads();
      // gates(q, jb-half) = (h_hi + h_lo) @ W^T ; 4 accumulators (dep-chain /4)
      f32x4 ac0 = {0.f,0.f,0.f,0.f}, ac1 = ac0, ac2 = ac0, ac3 = ac0;
      const int nrow = q * 32 + jb * 16 + lr;
      const int nbase = nrow * 1024, nx = nrow & 7;
      #pragma unroll
      for (int ks = 0; ks < 16; ks += 2){
        {
          const int s = ks * 4 + lh;
          const int aoff = lr * 1024 + ((s ^ (lr & 7)) << 4);
          const short8 ahi = *(const short8*)(hb + aoff);
          const short8 alo = *(const short8*)(hb2 + aoff);
          const short8 bv  = *(const short8*)(Wl + nbase + ((s ^ nx) << 4));
          ac0 = __builtin_amdgcn_mfma_f32_16x16x32_bf16(ahi, bv, ac0, 0, 0, 0);
          ac1 = __builtin_amdgcn_mfma_f32_16x16x32_bf16(alo, bv, ac1, 0, 0, 0);
        }
        {
          const int s = (ks + 1) * 4 + lh;
          const int aoff = lr * 1024 + ((s ^ (lr & 7)) << 4);
          const short8 ahi = *(const short8*)(hb + aoff);
          const short8 alo = *(const short8*)(hb2 + aoff);
          const short8 bv  = *(const short8*)(Wl + nbase + ((s ^ nx) << 4));
          ac2 = __builtin_amdgcn_mfma_f32_16x16x32_bf16(ahi, bv, ac2, 0, 0, 0);
          ac3 = __builtin_amdgcn_mfma_f32_16x16x32_bf16(alo, bv, ac3, 0, 0, 0);
        }
      }
      const f32x4 accs = (ac0 + ac1) + (ac2 + ac3);
      __syncthreads();   // all waves done reading hb/hb2 (gbuf aliases them)
      #pragma unroll
      for (int r = 0; r < 4; ++r)
        gbuf[(q * 16 + lh * 4 + r) * 32 + jb * 16 + lr] = accs[r];
      __syncthreads();
    }
    if (t == 0) asm volatile("s_waitcnt vmcnt(0)" ::: "memory");
    // pin: xv* consumed only after the drain above (keeps compiler honest)
    asm volatile("" : "+v"(xv0), "+v"(xv1), "+v"(xv2), "+v"(xv3));

    // ---- pointwise LSTM cell
    float g4[4];
    {
      union { u32 u; _Float16 h2[2]; } cv;
      cv.u = xv0; g4[0] = (float)cv.h2[0] + bias_[0];
      cv.u = xv1; g4[1] = (float)cv.h2[0] + bias_[1];
      cv.u = xv2; g4[2] = (float)cv.h2[0] + bias_[2];
      cv.u = xv3; g4[3] = (float)cv.h2[0] + bias_[3];
    }
    if (t > 0){
      #pragma unroll
      for (int qq = 0; qq < 4; ++qq) g4[qq] += gbuf[(qq * 16 + brow) * 32 + jj];
    }
    const float i_ = 1.f / (1.f + __expf(-g4[0]));
    const float f_ = 1.f / (1.f + __expf(-g4[1]));
    const float ea = __expf(-2.f * fabsf(g4[2]));
    const float g_ = __builtin_copysignf((1.f - ea) / (1.f + ea), g4[2]);
    const float o_ = 1.f / (1.f + __expf(-g4[3]));
    c = f_ * c + i_ * g_;
    const float eb = __expf(-2.f * fabsf(c));
    const float th = __builtin_copysignf((1.f - eb) / (1.f + eb), c);
    const float hn = o_ * th;

    if (t < TT - 1){
      // store h[t] device-coherent, drain, barrier, publish
      const size_t par = (size_t)(t & 1) * (BB * HH);
      const u16 hv = f2bf(hn);
      const u16 lov = f2bf(hn - bf2f(hv));
      u16* ph = h_hi + par + (size_t)(b0 + brow) * HH + j0 + jj;
      u16* pl = h_lo + par + (size_t)(b0 + brow) * HH + j0 + jj;
      asm volatile(
        "global_store_short %0, %2, off sc0 sc1\n\t"
        "global_store_short %1, %3, off sc0 sc1"
        :: "v"(ph), "v"(pl), "v"(hv), "v"(lov) : "memory");
      asm volatile("s_waitcnt vmcnt(0)" ::: "memory");
      __syncthreads();
      if (tid == 0)
        asm volatile("global_atomic_add %0, %1, off sc1" :: "v"(mycnt), "v"(1u) : "memory");
    }
    // out store off the critical path (after publish)
    out[(size_t)t * (BB * HH) + (size_t)(b0 + brow) * HH + j0 + jj] = c;
  }
}

// ---------------------------------------------------------------------------
extern "C" void kernel_launch(void* const* d_in, const int* in_sizes, int n_in,
                              void* d_out, int out_size, void* d_ws, size_t ws_size,
                              hipStream_t stream){
  const float* x    = (const float*)d_in[0];
  const float* w_ih = (const float*)d_in[1];
  const float* w_hh = (const float*)d_in[2];
  const float* b_ih = (const float*)d_in[3];
  const float* b_hh = (const float*)d_in[4];
  float* out = (float*)d_out;
  char* ws = (char*)d_ws;

  const size_t o_xg  = 0;             // fp16 [400][256][2048]   = 419,430,400 B
  const size_t o_xt2 = 419430400;     // bf16 [400][256][512]    = 104,857,600 B
  const size_t o_wp  = 524288000;     // bf16 [2048][512]        =   2,097,152 B
  const size_t o_hhi = 526385152;     // bf16 [2][256][512]      =     524,288 B
  const size_t o_hlo = 526909440;     //                         =     524,288 B
  const size_t o_cnt = 527433728;     // u32 counters, 16 x 256B =       4,096 B
  const size_t need  = 527437824;
  if (ws_size < need) return;

  _Float16* xg = (_Float16*)(ws + o_xg);
  u16* xt2 = (u16*)(ws + o_xt2);
  u16* wp  = (u16*)(ws + o_wp);
  u16* hhi = (u16*)(ws + o_hhi);
  u16* hlo = (u16*)(ws + o_hlo);
  u32* cnt = (u32*)(ws + o_cnt);

  hipMemsetAsync(cnt, 0, 4096, stream);
  hipLaunchKernelGGL(k_prep_x, dim3(102400), dim3(256), 0, stream, x, xt2);
  hipLaunchKernelGGL(k_prep_w, dim3(512), dim3(256), 0, stream, w_ih, wp);
  hipLaunchKernelGGL(k_gemm_xg, dim3(12800), dim3(256), 0, stream, xt2, wp, xg);
  hipLaunchKernelGGL(k_lstm, dim3(256), dim3(512), 163840, stream,
                     xg, w_hh, b_ih, b_hh, hhi, hlo, cnt, out);
}